// Round 1
// 91.831 us; speedup vs baseline: 1.0534x; 1.0534x over previous
//
#include <hip/hip_runtime.h>
#include <hip/hip_bf16.h>
#include <cstdint>

#define B_SZ  4096
#define N_POS 512
#define N_CLS 512
#define PHI   128
#define H1D   512
#define H2D   256

#define HS 520   // hist/h1 LDS row stride in bf16 (512+8: bank-conflict-free)
#define US 136   // u LDS row stride in bf16 (128+8)

typedef short bf16x8 __attribute__((ext_vector_type(8)));
typedef float f32x4  __attribute__((ext_vector_type(4)));

__device__ __forceinline__ unsigned int bf16rne(float f) {
  unsigned int x = __float_as_uint(f);
  return (x + 0x7fffu + ((x >> 16) & 1u)) >> 16;
}

// ---------------------------------------------------------------------------
// prep (R1 rewrite): coalesced LDS-tile transposes + parallel b1eff.
//  blocks 0..63    : W_phi (512x128 f32) -> WphiT (128x512 bf16), 32x32 tiles
//  blocks 64..127  : W1    (128x512 f32) -> W1T   (512x128 bf16)
//  blocks 128..255 : W2    (512x256 f32) -> W2T   (256x512 bf16)
//  blocks 256..263 : b1eff[j] = b1[j] + 512*(b_phi @ W1[:,j]), 64 j/block,
//                    4 p-groups x 32 coalesced MACs + LDS reduce.
// Old prep did 4B strided loads (stride 512B/1KB/2KB): ~16x fetch inflation
// (~16-20MB HBM post-poison) + a 2-block b1eff tail (128 loads/thread on 2
// CUs). New form: float4 coalesced loads (~1MB total fetch), 1 load/thread,
// tail is 32 loads deep on 8 blocks.
// NOTE (R7 post-mortem, prior session): do NOT merge prep into `fused` via
// grid.sync() — cooperative grid barrier on gfx950 costs ~70 µs. The kernel
// boundary is the cheap barrier.
// ---------------------------------------------------------------------------
__global__ __launch_bounds__(256) void prep(
    const float* __restrict__ W_phi, const float* __restrict__ W1,
    const float* __restrict__ W2, const float* __restrict__ b_phi,
    const float* __restrict__ b1,
    unsigned short* __restrict__ WphiT, unsigned short* __restrict__ W1T,
    unsigned short* __restrict__ W2T, float* __restrict__ b1eff) {
  __shared__ float ld[32][33];     // transpose tile (+1 pad: conflict-free)
  __shared__ float red2[4][64];    // b1eff partial sums

  const int b = blockIdx.x, t = threadIdx.x;

  if (b < 256) {
    const float* src;
    unsigned short* dst;
    int R, C, tr, tc;
    if (b < 64)       { src = W_phi; dst = WphiT; R = 512; C = 128; tr = b >> 2;         tc = b & 3; }
    else if (b < 128) { src = W1;    dst = W1T;   R = 128; C = 512; tr = (b - 64) >> 4;  tc = (b - 64) & 15; }
    else              { src = W2;    dst = W2T;   R = 512; C = 256; tr = (b - 128) >> 3; tc = (b - 128) & 7; }
    const int r0 = tr * 32, c0 = tc * 32;

    // coalesced load: 32 rows x 32 cols, float4 per thread (8 threads/row)
    const int lr = t >> 3, lc = (t & 7) * 4;
    float4 v = *(const float4*)(src + (size_t)(r0 + lr) * C + c0 + lc);
    ld[lr][lc + 0] = v.x; ld[lr][lc + 1] = v.y;
    ld[lr][lc + 2] = v.z; ld[lr][lc + 3] = v.w;
    __syncthreads();

    // coalesced store: out[c][r], ushort4 per thread.
    // out[c0+orr][r0+oc+i] = src[r0+oc+i][c0+orr] = ld[oc+i][orr]
    const int orr = t >> 3, oc = (t & 7) * 4;
    ushort4 o;
    o.x = (unsigned short)bf16rne(ld[oc + 0][orr]);
    o.y = (unsigned short)bf16rne(ld[oc + 1][orr]);
    o.z = (unsigned short)bf16rne(ld[oc + 2][orr]);
    o.w = (unsigned short)bf16rne(ld[oc + 3][orr]);
    *(ushort4*)(dst + (size_t)(c0 + orr) * R + r0 + oc) = o;
  } else {
    const int bb = b - 256;
    const int jj = t & 63, pg = t >> 6;
    const int j = bb * 64 + jj;
    float s = 0.0f;
    #pragma unroll 8
    for (int p = pg * 32; p < pg * 32 + 32; ++p)
      s += b_phi[p] * W1[p * H1D + j];   // coalesced across jj
    red2[pg][jj] = s;
    __syncthreads();
    if (pg == 0) {
      float a = red2[0][jj] + red2[1][jj] + red2[2][jj] + red2[3][jj];
      b1eff[j] = b1[j] + 512.0f * a;
    }
  }
}

// ---------------------------------------------------------------------------
// fused: unchanged from the 95.4 µs baseline (isolate the prep effect).
// per block of 16 batch rows (256 blocks, 512 threads = 8 waves):
//   hist (LDS atomics) -> u = Hist@WphiT^T -> h1 = relu(u@W1T^T + b1eff)
//   -> h2 = relu(h1@W2T^T + b2) -> out = h2@W3 + b3
// ---------------------------------------------------------------------------
__global__ __launch_bounds__(512) void fused(
    const int* __restrict__ x,
    const unsigned short* __restrict__ WphiT,
    const unsigned short* __restrict__ W1T,
    const unsigned short* __restrict__ W2T,
    const float* __restrict__ b1eff, const float* __restrict__ b2,
    const float* __restrict__ W3, const float* __restrict__ b3,
    float* __restrict__ out) {
  __shared__ unsigned int   hs[16 * 512];       // 32 KB
  __shared__ unsigned short hist_bf[16 * HS];   // 16.25 KB
  __shared__ unsigned short u_bf[16 * US];      // 4.25 KB
  __shared__ unsigned short h1_bf[16 * HS];     // 16.25 KB
  __shared__ float red[8][16];

  const int tid = threadIdx.x;
  const int w = tid >> 6, l = tid & 63;
  const int r = l & 15, q = l >> 4;
  const int bm = blockIdx.x * 16;

  // ---- phase 0: histogram of 16 rows (32 threads/row, 16 positions each) ----
  uint4* hs4 = (uint4*)hs;
  #pragma unroll
  for (int i = 0; i < 4; ++i) hs4[tid * 4 + i] = make_uint4(0, 0, 0, 0);
  __syncthreads();
  {
    const int row = tid >> 5, sub = tid & 31;
    const int* xp = x + (size_t)(bm + row) * N_POS + sub * 16;
    #pragma unroll
    for (int i = 0; i < 4; ++i) {
      int4 c = *(const int4*)(xp + i * 4);
      atomicAdd(&hs[row * 512 + c.x], 1u);
      atomicAdd(&hs[row * 512 + c.y], 1u);
      atomicAdd(&hs[row * 512 + c.z], 1u);
      atomicAdd(&hs[row * 512 + c.w], 1u);
    }
  }
  __syncthreads();
  {
    // counts <= 512 always -> bf16 exact
    const int row = tid >> 5, sub = tid & 31;
    const unsigned int* src = hs + row * 512 + sub * 16;
    unsigned short* dst = hist_bf + row * HS + sub * 16;
    #pragma unroll
    for (int i = 0; i < 2; ++i) {
      uint4 a = *(const uint4*)(src + i * 8);
      uint4 bq = *(const uint4*)(src + i * 8 + 4);
      uint4 o;
      o.x = bf16rne((float)a.x)  | (bf16rne((float)a.y)  << 16);
      o.y = bf16rne((float)a.z)  | (bf16rne((float)a.w)  << 16);
      o.z = bf16rne((float)bq.x) | (bf16rne((float)bq.y) << 16);
      o.w = bf16rne((float)bq.z) | (bf16rne((float)bq.w) << 16);
      *(uint4*)(dst + i * 8) = o;
    }
  }
  __syncthreads();

  // ---- phase 1: u = Hist @ WphiT^T  (K=512, N=128; wave w -> cols 16w..16w+15)
  f32x4 accu = (f32x4){0.f, 0.f, 0.f, 0.f};
  #pragma unroll 4
  for (int k0 = 0; k0 < N_CLS; k0 += 32) {
    bf16x8 af = *(const bf16x8*)&hist_bf[r * HS + k0 + q * 8];
    bf16x8 bfr = *(const bf16x8*)(WphiT + (size_t)(16 * w + r) * N_CLS + k0 + q * 8);
    accu = __builtin_amdgcn_mfma_f32_16x16x32_bf16(af, bfr, accu, 0, 0, 0);
  }
  #pragma unroll
  for (int reg = 0; reg < 4; ++reg)
    u_bf[(q * 4 + reg) * US + 16 * w + r] = (unsigned short)bf16rne(accu[reg]);
  __syncthreads();

  // ---- phase 2: h1 = relu(u @ W1T^T + b1eff)  (K=128, N=512; wave w -> cols 64w..)
  f32x4 acc1[4];
  #pragma unroll
  for (int j = 0; j < 4; ++j) acc1[j] = (f32x4){0.f, 0.f, 0.f, 0.f};
  #pragma unroll
  for (int k0 = 0; k0 < PHI; k0 += 32) {
    bf16x8 af = *(const bf16x8*)&u_bf[r * US + k0 + q * 8];
    #pragma unroll
    for (int tt = 0; tt < 4; ++tt) {
      bf16x8 bfr = *(const bf16x8*)(W1T + (size_t)(64 * w + 16 * tt + r) * PHI + k0 + q * 8);
      acc1[tt] = __builtin_amdgcn_mfma_f32_16x16x32_bf16(af, bfr, acc1[tt], 0, 0, 0);
    }
  }
  #pragma unroll
  for (int tt = 0; tt < 4; ++tt) {
    const int col = 64 * w + 16 * tt + r;
    const float bv = b1eff[col];
    #pragma unroll
    for (int reg = 0; reg < 4; ++reg) {
      float v = fmaxf(acc1[tt][reg] + bv, 0.0f);
      h1_bf[(q * 4 + reg) * HS + col] = (unsigned short)bf16rne(v);
    }
  }
  __syncthreads();

  // ---- phase 3: h2 = relu(h1 @ W2T^T + b2); out = h2 @ W3 + b3
  //      (K=512, N=256; wave w -> cols 32w..32w+31)
  f32x4 acc2[2];
  acc2[0] = (f32x4){0.f, 0.f, 0.f, 0.f};
  acc2[1] = (f32x4){0.f, 0.f, 0.f, 0.f};
  #pragma unroll 4
  for (int k0 = 0; k0 < H1D; k0 += 32) {
    bf16x8 af = *(const bf16x8*)&h1_bf[r * HS + k0 + q * 8];
    #pragma unroll
    for (int tt = 0; tt < 2; ++tt) {
      bf16x8 bfr = *(const bf16x8*)(W2T + (size_t)(32 * w + 16 * tt + r) * H1D + k0 + q * 8);
      acc2[tt] = __builtin_amdgcn_mfma_f32_16x16x32_bf16(af, bfr, acc2[tt], 0, 0, 0);
    }
  }
  float part[4] = {0.f, 0.f, 0.f, 0.f};
  #pragma unroll
  for (int tt = 0; tt < 2; ++tt) {
    const int col = 32 * w + 16 * tt + r;
    const float bv = b2[col];
    const float w3 = W3[col];
    #pragma unroll
    for (int reg = 0; reg < 4; ++reg)
      part[reg] += fmaxf(acc2[tt][reg] + bv, 0.0f) * w3;
  }
  #pragma unroll
  for (int off = 1; off < 16; off <<= 1)
    #pragma unroll
    for (int reg = 0; reg < 4; ++reg)
      part[reg] += __shfl_xor(part[reg], off, 64);
  if (r == 0)
    #pragma unroll
    for (int reg = 0; reg < 4; ++reg) red[w][q * 4 + reg] = part[reg];
  __syncthreads();
  if (tid < 16) {
    float s = b3[0];
    #pragma unroll
    for (int ww = 0; ww < 8; ++ww) s += red[ww][tid];
    out[bm + tid] = s;
  }
}

// ---------------------------------------------------------------------------
extern "C" void kernel_launch(void* const* d_in, const int* in_sizes, int n_in,
                              void* d_out, int out_size, void* d_ws, size_t ws_size,
                              hipStream_t stream) {
  const int*   x     = (const int*)  d_in[0];
  const float* W_phi = (const float*)d_in[1];
  const float* b_phi = (const float*)d_in[2];
  const float* W1    = (const float*)d_in[3];
  const float* b1    = (const float*)d_in[4];
  const float* W2    = (const float*)d_in[5];
  const float* b2    = (const float*)d_in[6];
  const float* W3    = (const float*)d_in[7];
  const float* b3    = (const float*)d_in[8];
  float* out = (float*)d_out;

  char* ws = (char*)d_ws;
  unsigned short* WphiT = (unsigned short*)(ws);            // 128 KB
  unsigned short* W1T   = (unsigned short*)(ws + 131072);   // 128 KB
  unsigned short* W2T   = (unsigned short*)(ws + 262144);   // 256 KB
  float*          b1eff = (float*)         (ws + 524288);   // 2 KB

  prep<<<264, 256, 0, stream>>>(W_phi, W1, W2, b_phi, b1,
                                WphiT, W1T, W2T, b1eff);
  fused<<<B_SZ / 16, 512, 0, stream>>>(x, WphiT, W1T, W2T,
                                       b1eff, b2, W3, b3, out);
}

// Round 3
// 91.098 us; speedup vs baseline: 1.0619x; 1.0080x over previous
//
#include <hip/hip_runtime.h>
#include <hip/hip_bf16.h>
#include <cstdint>

#define B_SZ  4096
#define N_POS 512
#define N_CLS 512
#define PHI   128
#define H1D   512
#define H2D   256

#define HS 520   // hist/h1 LDS row stride in bf16 (512+8: bank-conflict-free)
#define US 136   // u LDS row stride in bf16 (128+8)

typedef short bf16x8 __attribute__((ext_vector_type(8)));
typedef float f32x4  __attribute__((ext_vector_type(4)));

__device__ __forceinline__ unsigned int bf16rne(float f) {
  unsigned int x = __float_as_uint(f);
  return (x + 0x7fffu + ((x >> 16) & 1u)) >> 16;
}

// ---------------------------------------------------------------------------
// prep (unchanged from R1: coalesced LDS-tile transposes + parallel b1eff).
//  blocks 0..63    : W_phi (512x128 f32) -> WphiT (128x512 bf16), 32x32 tiles
//  blocks 64..127  : W1    (128x512 f32) -> W1T   (512x128 bf16)
//  blocks 128..255 : W2    (512x256 f32) -> W2T   (256x512 bf16)
//  blocks 256..263 : b1eff[j] = b1[j] + 512*(b_phi @ W1[:,j])
// NOTE (prior session R7 post-mortem): do NOT merge prep into `fused` via
// grid.sync() — cooperative grid barrier on gfx950 costs ~70 µs. The kernel
// boundary is the cheap barrier. Same reason we avoid a spin-flag fusion:
// block co-residency is not guaranteed once fused needs >1 block/CU slots.
// ---------------------------------------------------------------------------
__global__ __launch_bounds__(256) void prep(
    const float* __restrict__ W_phi, const float* __restrict__ W1,
    const float* __restrict__ W2, const float* __restrict__ b_phi,
    const float* __restrict__ b1,
    unsigned short* __restrict__ WphiT, unsigned short* __restrict__ W1T,
    unsigned short* __restrict__ W2T, float* __restrict__ b1eff) {
  __shared__ float ld[32][33];     // transpose tile (+1 pad: conflict-free)
  __shared__ float red2[4][64];    // b1eff partial sums

  const int b = blockIdx.x, t = threadIdx.x;

  if (b < 256) {
    const float* src;
    unsigned short* dst;
    int R, C, tr, tc;
    if (b < 64)       { src = W_phi; dst = WphiT; R = 512; C = 128; tr = b >> 2;         tc = b & 3; }
    else if (b < 128) { src = W1;    dst = W1T;   R = 128; C = 512; tr = (b - 64) >> 4;  tc = (b - 64) & 15; }
    else              { src = W2;    dst = W2T;   R = 512; C = 256; tr = (b - 128) >> 3; tc = (b - 128) & 7; }
    const int r0 = tr * 32, c0 = tc * 32;

    // coalesced load: 32 rows x 32 cols, float4 per thread (8 threads/row)
    const int lr = t >> 3, lc = (t & 7) * 4;
    float4 v = *(const float4*)(src + (size_t)(r0 + lr) * C + c0 + lc);
    ld[lr][lc + 0] = v.x; ld[lr][lc + 1] = v.y;
    ld[lr][lc + 2] = v.z; ld[lr][lc + 3] = v.w;
    __syncthreads();

    // coalesced store: out[c][r], ushort4 per thread.
    const int orr = t >> 3, oc = (t & 7) * 4;
    ushort4 o;
    o.x = (unsigned short)bf16rne(ld[oc + 0][orr]);
    o.y = (unsigned short)bf16rne(ld[oc + 1][orr]);
    o.z = (unsigned short)bf16rne(ld[oc + 2][orr]);
    o.w = (unsigned short)bf16rne(ld[oc + 3][orr]);
    *(ushort4*)(dst + (size_t)(c0 + orr) * R + r0 + oc) = o;
  } else {
    const int bb = b - 256;
    const int jj = t & 63, pg = t >> 6;
    const int j = bb * 64 + jj;
    float s = 0.0f;
    #pragma unroll 8
    for (int p = pg * 32; p < pg * 32 + 32; ++p)
      s += b_phi[p] * W1[p * H1D + j];   // coalesced across jj
    red2[pg][jj] = s;
    __syncthreads();
    if (pg == 0) {
      float a = red2[0][jj] + red2[1][jj] + red2[2][jj] + red2[3][jj];
      b1eff[j] = b1[j] + 512.0f * a;
    }
  }
}

// ---------------------------------------------------------------------------
// fused (R2 resubmit: software-pipelined weight prefetch; math identical).
// per block of 16 batch rows (256 blocks = 1/CU, 512 threads = 8 waves):
//   hist (LDS atomics) -> u = Hist@WphiT^T -> h1 = relu(u@W1T^T + b1eff)
//   -> h2 = relu(h1@W2T^T + b2) -> out = h2@W3 + b3
// Prefetch schedule: x + WphiT frags issued before hist; W1T frags issued
// under phase 1; W2T first half issued under phase 2, rest in-loop.
// Peak regs ~180 -> 2 waves/SIMD holds (launch_bounds(512,2)).
// ---------------------------------------------------------------------------
__global__ __launch_bounds__(512, 2) void fused(
    const int* __restrict__ x,
    const unsigned short* __restrict__ WphiT,
    const unsigned short* __restrict__ W1T,
    const unsigned short* __restrict__ W2T,
    const float* __restrict__ b1eff, const float* __restrict__ b2,
    const float* __restrict__ W3, const float* __restrict__ b3,
    float* __restrict__ out) {
  __shared__ unsigned int   hs[16 * 512];       // 32 KB
  __shared__ unsigned short hist_bf[16 * HS];   // 16.25 KB
  __shared__ unsigned short u_bf[16 * US];      // 4.25 KB
  __shared__ unsigned short h1_bf[16 * HS];     // 16.25 KB
  __shared__ float red[8][16];

  const int tid = threadIdx.x;
  const int w = tid >> 6, l = tid & 63;
  const int r = l & 15, q = l >> 4;
  const int bm = blockIdx.x * 16;

  // ---- prefetch: x rows (HBM) + phase-1 WphiT fragments (L2/L3) ----
  const int row = tid >> 5, sub = tid & 31;
  const int* xp = x + (size_t)(bm + row) * N_POS + sub * 16;
  int4 xc[4];
  #pragma unroll
  for (int i = 0; i < 4; ++i) xc[i] = *(const int4*)(xp + i * 4);

  const unsigned short* wpp = WphiT + (size_t)(16 * w + r) * N_CLS + q * 8;
  bf16x8 wp[16];
  #pragma unroll
  for (int kk = 0; kk < 16; ++kk) wp[kk] = *(const bf16x8*)(wpp + kk * 32);

  // ---- phase 0: histogram of 16 rows (32 threads/row, 16 positions each) ----
  uint4* hs4 = (uint4*)hs;
  #pragma unroll
  for (int i = 0; i < 4; ++i) hs4[tid * 4 + i] = make_uint4(0, 0, 0, 0);
  __syncthreads();
  #pragma unroll
  for (int i = 0; i < 4; ++i) {
    atomicAdd(&hs[row * 512 + xc[i].x], 1u);
    atomicAdd(&hs[row * 512 + xc[i].y], 1u);
    atomicAdd(&hs[row * 512 + xc[i].z], 1u);
    atomicAdd(&hs[row * 512 + xc[i].w], 1u);
  }
  __syncthreads();
  {
    // counts <= 512 always -> bf16 exact
    const unsigned int* src = hs + row * 512 + sub * 16;
    unsigned short* dst = hist_bf + row * HS + sub * 16;
    #pragma unroll
    for (int i = 0; i < 2; ++i) {
      uint4 a = *(const uint4*)(src + i * 8);
      uint4 bq = *(const uint4*)(src + i * 8 + 4);
      uint4 o;
      o.x = bf16rne((float)a.x)  | (bf16rne((float)a.y)  << 16);
      o.y = bf16rne((float)a.z)  | (bf16rne((float)a.w)  << 16);
      o.z = bf16rne((float)bq.x) | (bf16rne((float)bq.y) << 16);
      o.w = bf16rne((float)bq.z) | (bf16rne((float)bq.w) << 16);
      *(uint4*)(dst + i * 8) = o;
    }
  }
  __syncthreads();

  // ---- prefetch phase-2 W1T fragments (hidden under phase-1 MFMAs) ----
  const unsigned short* w1p = W1T + (size_t)(64 * w + r) * PHI + q * 8;
  bf16x8 w1f[16];
  #pragma unroll
  for (int kk = 0; kk < 4; ++kk)
    #pragma unroll
    for (int tt = 0; tt < 4; ++tt)
      w1f[kk * 4 + tt] = *(const bf16x8*)(w1p + (size_t)(16 * tt) * PHI + kk * 32);

  // ---- phase 1: u = Hist @ WphiT^T  (K=512, N=128; wave w -> cols 16w..16w+15)
  f32x4 accu = (f32x4){0.f, 0.f, 0.f, 0.f};
  #pragma unroll
  for (int kk = 0; kk < 16; ++kk) {
    bf16x8 af = *(const bf16x8*)&hist_bf[r * HS + kk * 32 + q * 8];
    accu = __builtin_amdgcn_mfma_f32_16x16x32_bf16(af, wp[kk], accu, 0, 0, 0);
  }
  #pragma unroll
  for (int reg = 0; reg < 4; ++reg)
    u_bf[(q * 4 + reg) * US + 16 * w + r] = (unsigned short)bf16rne(accu[reg]);
  __syncthreads();

  // ---- prefetch phase-3 W2T fragments, first 8 k-steps (under phase 2) ----
  const unsigned short* w2p = W2T + (size_t)(32 * w + r) * H1D + q * 8;
  bf16x8 w2f[16];
  #pragma unroll
  for (int kk = 0; kk < 8; ++kk)
    #pragma unroll
    for (int tt = 0; tt < 2; ++tt)
      w2f[kk * 2 + tt] = *(const bf16x8*)(w2p + (size_t)(16 * tt) * H1D + kk * 32);

  // ---- phase 2: h1 = relu(u @ W1T^T + b1eff)  (K=128, N=512; wave w -> cols 64w..)
  f32x4 acc1[4];
  #pragma unroll
  for (int j = 0; j < 4; ++j) acc1[j] = (f32x4){0.f, 0.f, 0.f, 0.f};
  #pragma unroll
  for (int kk = 0; kk < 4; ++kk) {
    bf16x8 af = *(const bf16x8*)&u_bf[r * US + kk * 32 + q * 8];
    #pragma unroll
    for (int tt = 0; tt < 4; ++tt)
      acc1[tt] = __builtin_amdgcn_mfma_f32_16x16x32_bf16(af, w1f[kk * 4 + tt], acc1[tt], 0, 0, 0);
  }
  #pragma unroll
  for (int tt = 0; tt < 4; ++tt) {
    const int col = 64 * w + 16 * tt + r;
    const float bv = b1eff[col];
    #pragma unroll
    for (int reg = 0; reg < 4; ++reg) {
      float v = fmaxf(acc1[tt][reg] + bv, 0.0f);
      h1_bf[(q * 4 + reg) * HS + col] = (unsigned short)bf16rne(v);
    }
  }
  __syncthreads();

  // ---- phase 3: h2 = relu(h1 @ W2T^T + b2); out = h2 @ W3 + b3
  //      (K=512, N=256; wave w -> cols 32w..32w+31)
  f32x4 acc2[2];
  acc2[0] = (f32x4){0.f, 0.f, 0.f, 0.f};
  acc2[1] = (f32x4){0.f, 0.f, 0.f, 0.f};
  #pragma unroll
  for (int kk = 0; kk < 16; ++kk) {
    bf16x8 af = *(const bf16x8*)&h1_bf[r * HS + kk * 32 + q * 8];
    #pragma unroll
    for (int tt = 0; tt < 2; ++tt) {
      bf16x8 bfr = (kk < 8)
          ? w2f[kk * 2 + tt]
          : *(const bf16x8*)(w2p + (size_t)(16 * tt) * H1D + kk * 32);
      acc2[tt] = __builtin_amdgcn_mfma_f32_16x16x32_bf16(af, bfr, acc2[tt], 0, 0, 0);
    }
  }
  float part[4] = {0.f, 0.f, 0.f, 0.f};
  #pragma unroll
  for (int tt = 0; tt < 2; ++tt) {
    const int col = 32 * w + 16 * tt + r;
    const float bv = b2[col];
    const float w3 = W3[col];
    #pragma unroll
    for (int reg = 0; reg < 4; ++reg)
      part[reg] += fmaxf(acc2[tt][reg] + bv, 0.0f) * w3;
  }
  #pragma unroll
  for (int off = 1; off < 16; off <<= 1)
    #pragma unroll
    for (int reg = 0; reg < 4; ++reg)
      part[reg] += __shfl_xor(part[reg], off, 64);
  if (r == 0)
    #pragma unroll
    for (int reg = 0; reg < 4; ++reg) red[w][q * 4 + reg] = part[reg];
  __syncthreads();
  if (tid < 16) {
    float s = b3[0];
    #pragma unroll
    for (int ww = 0; ww < 8; ++ww) s += red[ww][tid];
    out[bm + tid] = s;
  }
}

// ---------------------------------------------------------------------------
extern "C" void kernel_launch(void* const* d_in, const int* in_sizes, int n_in,
                              void* d_out, int out_size, void* d_ws, size_t ws_size,
                              hipStream_t stream) {
  const int*   x     = (const int*)  d_in[0];
  const float* W_phi = (const float*)d_in[1];
  const float* b_phi = (const float*)d_in[2];
  const float* W1    = (const float*)d_in[3];
  const float* b1    = (const float*)d_in[4];
  const float* W2    = (const float*)d_in[5];
  const float* b2    = (const float*)d_in[6];
  const float* W3    = (const float*)d_in[7];
  const float* b3    = (const float*)d_in[8];
  float* out = (float*)d_out;

  char* ws = (char*)d_ws;
  unsigned short* WphiT = (unsigned short*)(ws);            // 128 KB
  unsigned short* W1T   = (unsigned short*)(ws + 131072);   // 128 KB
  unsigned short* W2T   = (unsigned short*)(ws + 262144);   // 256 KB
  float*          b1eff = (float*)         (ws + 524288);   // 2 KB

  prep<<<264, 256, 0, stream>>>(W_phi, W1, W2, b_phi, b1,
                                WphiT, W1T, W2T, b1eff);
  fused<<<B_SZ / 16, 512, 0, stream>>>(x, WphiT, W1T, W2T,
                                       b1eff, b2, W3, b3, out);
}